// Round 1
// baseline (32.692 us; speedup 1.0000x reference)
//
#include <hip/hip_runtime.h>

// Problem constants (from reference): B=4, N=512, K=20, C=32
#define Bb 4
#define Nn 512
#define Kk 20
#define Cc 32

// out[b, n, k, c1, c2] = trans[c1,c2] + length[k,c2] + slide[b,n,k,c2]
//                        + (k == (N-1)-n ? E[b,N-1,c1] : 0)
//                        + (n == 0 ? init[c2] : 0)
// slide[b,n,k,c2] = sum_{j=n}^{min(n+k,N)-1} E[b,j,c2]   (k frames, clipped)
//
// One block per (b,n). Thread layout: c1 = tid/8 (0..31), q = tid%8 (float4
// column along c2). Each thread emits K=20 float4 stores; consecutive tids
// cover a contiguous 4KB burst per k (fully coalesced). Sliding sum kept as
// a running float4 register accumulator across the k loop.
__global__ __launch_bounds__(256) void semimarkov_scores_kernel(
    const float* __restrict__ trans,   // (C,C)
    const float* __restrict__ emis,    // (B,N,C)
    const float* __restrict__ initv,   // (C,)
    const float* __restrict__ lens,    // (K,C)
    float* __restrict__ out)           // (B, N-1, K, C, C)
{
    const int tid = threadIdx.x;
    const int c1  = tid >> 3;          // 0..31
    const int q   = tid & 7;           // float4 index along c2 (c2 = 4q..4q+3)
    const int bn  = blockIdx.x;        // b*(N-1) + n
    const int b   = bn / (Nn - 1);
    const int n   = bn - b * (Nn - 1);

    // Per-thread invariant part: transition row chunk (+ init for n==0)
    float4 add4 = *reinterpret_cast<const float4*>(&trans[c1 * Cc + q * 4]);
    if (n == 0) {
        const float4 i4 = *reinterpret_cast<const float4*>(&initv[q * 4]);
        add4.x += i4.x; add4.y += i4.y; add4.z += i4.z; add4.w += i4.w;
    }

    // eos: added at k_eos = (N-1)-n (always >=1 here), only if k_eos < K.
    const int   k_eos  = (Nn - 1) - n;
    const float e_last = (k_eos < Kk)
        ? emis[((size_t)b * Nn + (Nn - 1)) * Cc + c1]
        : 0.0f;

    float4 s4 = make_float4(0.f, 0.f, 0.f, 0.f);   // running window sum (c2 chunk)
    const float* eb = &emis[((size_t)b * Nn + n) * Cc + q * 4];
    size_t obase = (size_t)bn * (size_t)(Kk * Cc * Cc) + (size_t)(c1 * Cc + q * 4);

    #pragma unroll
    for (int k = 0; k < Kk; ++k) {
        const float4 l4 = *reinterpret_cast<const float4*>(&lens[k * Cc + q * 4]);
        float4 v;
        v.x = add4.x + l4.x + s4.x;
        v.y = add4.y + l4.y + s4.y;
        v.z = add4.z + l4.z + s4.z;
        v.w = add4.w + l4.w + s4.w;
        if (k == k_eos) {
            v.x += e_last; v.y += e_last; v.z += e_last; v.w += e_last;
        }
        *reinterpret_cast<float4*>(&out[obase + (size_t)k * (Cc * Cc)]) = v;

        // extend window by frame n+k (exists iff n+k <= N-1)
        if (n + k < Nn) {
            const float4 e4 = *reinterpret_cast<const float4*>(&eb[(size_t)k * Cc]);
            s4.x += e4.x; s4.y += e4.y; s4.z += e4.z; s4.w += e4.w;
        }
    }
}

extern "C" void kernel_launch(void* const* d_in, const int* in_sizes, int n_in,
                              void* d_out, int out_size, void* d_ws, size_t ws_size,
                              hipStream_t stream) {
    const float* trans = (const float*)d_in[0];   // (C,C)
    const float* emis  = (const float*)d_in[1];   // (B,N,C)
    const float* initv = (const float*)d_in[2];   // (C,)
    const float* lens  = (const float*)d_in[3];   // (K,C)
    float* out = (float*)d_out;                   // (B, N-1, K, C, C)

    const int grid = Bb * (Nn - 1);               // 2044 blocks
    semimarkov_scores_kernel<<<grid, 256, 0, stream>>>(trans, emis, initv, lens, out);
}